// Round 4
// baseline (260.065 us; speedup 1.0000x reference)
//
#include <hip/hip_runtime.h>
#include <hip/hip_bf16.h>
#include <hip/hip_cooperative_groups.h>
#include <math.h>

namespace cg = cooperative_groups;

typedef __bf16 bf16x8 __attribute__((ext_vector_type(8)));
typedef float  f32x4  __attribute__((ext_vector_type(4)));

#define BB 2
#define C1 256
#define C2 256
#define HH 64
#define WW 64
#define HW 4096
#define OCH 27
#define EPSV 1e-5f

// workspace layout (bytes)
#define WBF_OFF  0u          // frag-ordered w_dcn (1.18 MB)
#define WOFF_OFF 1179648u    // frag-ordered w_off
#define XT_OFF   1327104u    // 2*4096*256 bf16 = 4 MB (HWC)

// ---------------------------------------------------------------------------
// MEGA kernel = prep + grid.sync + fused (R2 body verbatim).
// R3 post-mortem: prefetch regs under the 128-VGPR cap spilled to scratch
// (+13 MB FETCH/WRITE, +14 us) -> reverted to R2 main loop. Dispatch-ID
// spacing shows ~48 harness memset dispatches (~60 us fixed) per timed
// iteration; the controllable non-fused cost is prep + one launch gap
// (~14 us). This round merges prep into the fused kernel: 2 transpose
// units per block (512 thr), w_dcn frag units on blocks 0..63, w_off on
// 64..81, then threadfence + cooperative grid.sync + threadfence (cross-
// XCD L2 visibility), then the R2 fused body unchanged. 256 blocks at
// 82 KB LDS = 1 block/CU -> co-residency guaranteed for cooperative sync.
// ---------------------------------------------------------------------------
union SU {
    float  sD[8][2][16][33];   // phase -1 partials (67.6 KB)
    float  sC[4][32][133];     // main K-reduction, half-N passes (68.1 KB)
    __bf16 tile[2][64][72];    // prep: x-transpose staging (18.4 KB)
    __bf16 lw[16][584];        // prep: w_dcn staging (18.7 KB)
};

__global__ __launch_bounds__(512, 2) void mega_kernel(
    const float* __restrict__ x, const float* __restrict__ w_off,
    const float* __restrict__ w_dcn, const float* __restrict__ b_off,
    const float* __restrict__ gamma, const float* __restrict__ beta,
    const float* __restrict__ rmean, const float* __restrict__ rvar,
    float* __restrict__ out, __bf16* __restrict__ xT,
    __bf16* __restrict__ wbfS, __bf16* __restrict__ woffS)
{
    __shared__ SU u;
    __shared__ float  sOm[32][33];       // 4.2 KB
    __shared__ int4   sO[9][32];         // 4.6 KB
    __shared__ float4 sW[9][32];         // 4.6 KB

    const int tid = threadIdx.x, bid = blockIdx.x;

    // ================= PREP PHASE =================
    // --- x transpose: 512 units over 256 blocks, 2 per block ---
    {
        const int sub = tid >> 8, t8 = tid & 255;
        const int u2 = bid * 2 + sub;
        const int b = u2 >> 8;
        const int ht = (u2 & 255) >> 2;
        const int ct = u2 & 3;
        const int hw_l = t8 & 63, cg = t8 >> 6;
        const float* src = x + ((size_t)(b * 256 + ct * 64 + cg * 16) << 12)
                             + ht * 64 + hw_l;
        #pragma unroll
        for (int i = 0; i < 16; i++)
            u.tile[sub][hw_l][cg * 16 + i] = (__bf16)src[(size_t)i << 12];
        __syncthreads();
        const int hw_o = t8 >> 2, cq = t8 & 3;
        __bf16* dst = xT + ((size_t)(b * HW + ht * 64 + hw_o) << 8)
                         + ct * 64 + cq * 16;
        *(bf16x8*)dst       = *(const bf16x8*)&u.tile[sub][hw_o][cq * 16];
        *(bf16x8*)(dst + 8) = *(const bf16x8*)&u.tile[sub][hw_o][cq * 16 + 8];
    }
    __syncthreads();

    // --- w_dcn frag-order: 64 units on blocks 0..63 (tid<256 active) ---
    if (bid < 64) {
        const int nb = bid >> 2, qtr = bid & 3;
        if (tid < 256) {
            #pragma unroll
            for (int ii = 0; ii < 9; ii++) {
                int m = tid + 256 * ii;
                int base = m * 4;
                int o_l = base / 576;
                int f = base - o_l * 576;
                float4 v = *(const float4*)(w_dcn
                    + (size_t)(nb * 16 + o_l) * 2304 + qtr * 576 + f);
                u.lw[o_l][f]     = (__bf16)v.x;
                u.lw[o_l][f + 1] = (__bf16)v.y;
                u.lw[o_l][f + 2] = (__bf16)v.z;
                u.lw[o_l][f + 3] = (__bf16)v.w;
            }
        }
        __syncthreads();
        if (tid < 256) {
            for (int p = tid; p < 1152; p += 256) {
                int lane = p & 63, seg = p >> 6;
                int tap = seg >> 1, ks = seg & 1;
                int kb = tap * 4 + qtr;
                int o_l = lane & 15, kq = (lane >> 4) & 3;
                bf16x8 v;
                #pragma unroll
                for (int j = 0; j < 8; j++)
                    v[j] = u.lw[o_l][(ks * 32 + kq * 8 + j) * 9 + tap];
                *(bf16x8*)(wbfS
                    + ((size_t)(((kb * 2 + ks) * 16 + nb) * 64 + lane)) * 8) = v;
            }
        }
    } else if (bid < 82) {
        // --- w_off frag-order: 9216 frags on blocks 64..81, 512 thr ---
        int t = (bid - 64) * 512 + tid;
        int l = t & 63;
        int nf = (t >> 6) & 1;
        int ks = (t >> 7) & 1;
        int kb = t >> 8;
        int o = nf * 16 + (l & 15);
        int kq = (l >> 4) & 3;
        bf16x8 v;
        #pragma unroll
        for (int j = 0; j < 8; j++) {
            int K = kb * 64 + ks * 32 + kq * 8 + j;
            v[j] = (o < OCH) ? (__bf16)w_off[o * 2304 + (K & 255) * 9 + (K >> 8)]
                             : (__bf16)0.f;
        }
        *(bf16x8*)(woffS + (size_t)t * 8) = v;
    }

    // ---- device-scope release, grid barrier, acquire ----
    __threadfence();
    cg::this_grid().sync();
    __threadfence();
    __syncthreads();

    // ================= FUSED PHASE (R2 body, verbatim) =================
    const int wv = tid >> 6, lane = tid & 63;
    const int g = (bid & 7) * 32 + (bid >> 3);   // XCD swizzle
    const int pixBase = g * 32;
    const int b = pixBase >> 12;
    const int hwBase = pixBase & 4095;
    const int h = hwBase >> 6, w0 = hwBase & 63;   // 32 pixels in one row
    const int n15 = lane & 15, q4 = lane >> 4;

    const int cc  = wv >> 1;             // channel quarter (0..3)
    const int ksw = wv & 1;              // 32-ch half within quarter
    const char* xb = (const char*)xT + ((size_t)b << 12) * 512;
    const int chOffB = (cc * 64 + ksw * 32 + q4 * 8) * 2;  // byte off in row

    // ---------------- Phase -1: offset conv for 32 pixels ----------------
    {
        f32x4 acc2[2][2];                // [nf][tile]
        #pragma unroll
        for (int nf = 0; nf < 2; nf++)
            #pragma unroll
            for (int t = 0; t < 2; t++)
                acc2[nf][t] = (f32x4){0.f, 0.f, 0.f, 0.f};

        #pragma unroll
        for (int k = 0; k < 9; k++) {
            const int kb = k * 4 + cc;
            const int kh = k / 3, kw = k % 3;
            const int hh = h + kh - 1;
            const int hc = min(max(hh, 0), HH - 1);
            const bool vy = (hh >= 0) && (hh < HH);
            bf16x8 af[2];
            #pragma unroll
            for (int t = 0; t < 2; t++) {
                const int ww = w0 + t * 16 + n15 + kw - 1;
                const bool valid = vy && (ww >= 0) && (ww < WW);
                const int wc = min(max(ww, 0), WW - 1);
                af[t] = *(const bf16x8*)(xb + (size_t)(hc * WW + wc) * 512
                                            + chOffB);
                if (!valid) {
                    #pragma unroll
                    for (int j = 0; j < 8; j++) af[t][j] = (__bf16)0.f;
                }
            }
            #pragma unroll
            for (int nf = 0; nf < 2; nf++) {
                bf16x8 bfr = *(const bf16x8*)(woffS
                    + ((size_t)(((kb * 2 + ksw) * 2 + nf) * 64 + lane)) * 8);
                #pragma unroll
                for (int t = 0; t < 2; t++)
                    acc2[nf][t] = __builtin_amdgcn_mfma_f32_16x16x32_bf16(
                        af[t], bfr, acc2[nf][t], 0, 0, 0);
            }
        }
        #pragma unroll
        for (int nf = 0; nf < 2; nf++)
            #pragma unroll
            for (int t = 0; t < 2; t++)
                #pragma unroll
                for (int r = 0; r < 4; r++)
                    u.sD[wv][t][q4 * 4 + r][nf * 16 + n15] = acc2[nf][t][r];
    }
    __syncthreads();
    for (int t2 = tid; t2 < OCH * 32; t2 += 512) {
        int oc = t2 >> 5, p = t2 & 31;
        float s = b_off[oc];
        #pragma unroll
        for (int w = 0; w < 8; w++) s += u.sD[w][p >> 4][p & 15][oc];
        sOm[oc][p] = s;
    }
    __syncthreads();

    // ---------------- Phase 0: bilinear metadata for 32 pixels -----------
    if (tid < 288) {
        int k = tid >> 5, p = tid & 31;
        float dy = sOm[2 * k][p];
        float dx = sOm[2 * k + 1][p];
        float mm = sOm[18 + k][p];
        mm = 1.f / (1.f + __expf(-mm));
        float py = (float)(h - 1 + k / 3) + dy;
        float px = (float)(w0 + p - 1 + k % 3) + dx;
        float y0f = floorf(py), x0f = floorf(px);
        float ly = py - y0f, lx = px - x0f;
        int y0 = (int)y0f, x0 = (int)x0f;
        int yc0 = min(max(y0, 0), HH - 1),     yc1 = min(max(y0 + 1, 0), HH - 1);
        int xc0 = min(max(x0, 0), WW - 1),     xc1 = min(max(x0 + 1, 0), WW - 1);
        float vy0 = (y0 >= 0 && y0 < HH) ? 1.f : 0.f;
        float vy1 = (y0 + 1 >= 0 && y0 + 1 < HH) ? 1.f : 0.f;
        float vx0 = (x0 >= 0 && x0 < WW) ? 1.f : 0.f;
        float vx1 = (x0 + 1 >= 0 && x0 + 1 < WW) ? 1.f : 0.f;
        sO[k][p] = (int4){(yc0 * WW + xc0) * 512, (yc0 * WW + xc1) * 512,
                          (yc1 * WW + xc0) * 512, (yc1 * WW + xc1) * 512};
        sW[k][p] = (float4){(1.f - ly) * (1.f - lx) * vy0 * vx0 * mm,
                            (1.f - ly) * lx         * vy0 * vx1 * mm,
                            ly         * (1.f - lx) * vy1 * vx0 * mm,
                            ly         * lx         * vy1 * vx1 * mm};
    }
    __syncthreads();

    // ---------------- Main: barrier-free (cc,ks)-split GEMM, M=32 --------
    f32x4 acc[2][16];                    // [tile][n-col] = 128 regs
    #pragma unroll
    for (int t = 0; t < 2; t++)
        #pragma unroll
        for (int j = 0; j < 16; j++) acc[t][j] = (f32x4){0.f, 0.f, 0.f, 0.f};

    const char* base = xb + chOffB;
    for (int k = 0; k < 9; k++) {
        const int kb = k * 4 + cc;
        const int4   O0 = sO[k][n15],      O1 = sO[k][16 + n15];
        const float4 W0 = sW[k][n15],      W1 = sW[k][16 + n15];

        bf16x8 a00 = *(const bf16x8*)(base + O0.x);
        bf16x8 a01 = *(const bf16x8*)(base + O0.y);
        bf16x8 a10 = *(const bf16x8*)(base + O0.z);
        bf16x8 a11 = *(const bf16x8*)(base + O0.w);
        bf16x8 b00 = *(const bf16x8*)(base + O1.x);
        bf16x8 b01 = *(const bf16x8*)(base + O1.y);
        bf16x8 b10 = *(const bf16x8*)(base + O1.z);
        bf16x8 b11 = *(const bf16x8*)(base + O1.w);

        bf16x8 af0, af1;
        #pragma unroll
        for (int j = 0; j < 8; j++) {
            float v0 = W0.x * (float)a00[j] + W0.y * (float)a01[j]
                     + W0.z * (float)a10[j] + W0.w * (float)a11[j];
            float v1 = W1.x * (float)b00[j] + W1.y * (float)b01[j]
                     + W1.z * (float)b10[j] + W1.w * (float)b11[j];
            af0[j] = (__bf16)v0;
            af1[j] = (__bf16)v1;
        }

        #pragma unroll
        for (int hf = 0; hf < 2; hf++) {
            bf16x8 bfr[8];
            #pragma unroll
            for (int nb = 0; nb < 8; nb++)
                bfr[nb] = *(const bf16x8*)(wbfS
                    + ((size_t)(((kb * 2 + ksw) * 16 + hf * 8 + nb) * 64 + lane)) * 8);
            #pragma unroll
            for (int nb = 0; nb < 8; nb++) {
                acc[0][hf * 8 + nb] = __builtin_amdgcn_mfma_f32_16x16x32_bf16(
                    af0, bfr[nb], acc[0][hf * 8 + nb], 0, 0, 0);
                acc[1][hf * 8 + nb] = __builtin_amdgcn_mfma_f32_16x16x32_bf16(
                    af1, bfr[nb], acc[1][hf * 8 + nb], 0, 0, 0);
            }
        }
    }

    // ------- 2-pass cross-wave K-reduction + fused BN/SiLU epilogue -------
    #pragma unroll
    for (int pass = 0; pass < 2; pass++) {
        if (wv < 4) {
            #pragma unroll
            for (int t = 0; t < 2; t++)
                #pragma unroll
                for (int nb = 0; nb < 8; nb++)
                    #pragma unroll
                    for (int r = 0; r < 4; r++)
                        u.sC[wv][t * 16 + q4 * 4 + r][nb * 16 + n15]
                            = acc[t][pass * 8 + nb][r];
        }
        __syncthreads();
        if (wv >= 4) {
            #pragma unroll
            for (int t = 0; t < 2; t++)
                #pragma unroll
                for (int nb = 0; nb < 8; nb++)
                    #pragma unroll
                    for (int r = 0; r < 4; r++)
                        u.sC[wv - 4][t * 16 + q4 * 4 + r][nb * 16 + n15]
                            += acc[t][pass * 8 + nb][r];
        }
        __syncthreads();

        const int px = tid & 31, og = tid >> 5;   // og in [0,16)
        #pragma unroll
        for (int ii = 0; ii < 8; ii++) {
            int col = og * 8 + ii;               // [0,128)
            int o = pass * 128 + col;
            float s = u.sC[0][px][col] + u.sC[1][px][col]
                    + u.sC[2][px][col] + u.sC[3][px][col];
            float inv = gamma[o] * rsqrtf(rvar[o] + EPSV);
            float sh = beta[o] - rmean[o] * inv;
            float y = s * inv + sh;
            out[(size_t)((b * C2 + o) << 12) + hwBase + px]
                = y * (1.f / (1.f + __expf(-y)));
        }
        __syncthreads();
    }
}

// ---------------------------------------------------------------------------
extern "C" void kernel_launch(void* const* d_in, const int* in_sizes, int n_in,
                              void* d_out, int out_size, void* d_ws, size_t ws_size,
                              hipStream_t stream) {
    const float* x      = (const float*)d_in[0];
    const float* w_off  = (const float*)d_in[1];
    const float* b_off  = (const float*)d_in[2];
    const float* w_dcn  = (const float*)d_in[3];
    const float* gamma  = (const float*)d_in[4];
    const float* beta   = (const float*)d_in[5];
    const float* rmean  = (const float*)d_in[6];
    const float* rvar   = (const float*)d_in[7];
    float* out = (float*)d_out;

    char* ws = (char*)d_ws;
    __bf16* wbfS  = (__bf16*)(ws + WBF_OFF);
    __bf16* woffS = (__bf16*)(ws + WOFF_OFF);
    __bf16* xT    = (__bf16*)(ws + XT_OFF);

    void* args[] = {
        (void*)&x, (void*)&w_off, (void*)&w_dcn, (void*)&b_off,
        (void*)&gamma, (void*)&beta, (void*)&rmean, (void*)&rvar,
        (void*)&out, (void*)&xT, (void*)&wbfS, (void*)&woffS
    };
    hipLaunchCooperativeKernel((const void*)mega_kernel, dim3(256), dim3(512),
                               args, 0, stream);
}

// Round 5
// 119.834 us; speedup vs baseline: 2.1702x; 2.1702x over previous
//
#include <hip/hip_runtime.h>
#include <hip/hip_bf16.h>
#include <math.h>

typedef __bf16 bf16x8 __attribute__((ext_vector_type(8)));
typedef float  f32x4  __attribute__((ext_vector_type(4)));

#define BB 2
#define C1 256
#define C2 256
#define HH 64
#define WW 64
#define HW 4096
#define OCH 27
#define EPSV 1e-5f

// workspace layout (bytes)
#define WBF_OFF  0u          // frag-ordered w_dcn (1.18 MB)
#define WOFF_OFF 1179648u    // frag-ordered w_off
#define XT_OFF   1327104u    // 2*4096*256 bf16 = 4 MB (HWC)

// ---------------------------------------------------------------------------
// MERGED prep kernel (R2 verbatim; R4's cooperative merge cost -139 us and
// is reverted).
// ---------------------------------------------------------------------------
__global__ __launch_bounds__(256) void prep_kernel(
    const float* __restrict__ x, const float* __restrict__ w_dcn,
    const float* __restrict__ w_off, __bf16* __restrict__ xT,
    __bf16* __restrict__ wbfS, __bf16* __restrict__ woffS)
{
    __shared__ __bf16 tile[64][72];
    __shared__ __bf16 lw[16][584];
    const int bi = blockIdx.x, tid = threadIdx.x;

    if (bi < 512) {
        const int b = bi >> 8;
        const int ht = (bi & 255) >> 2;
        const int ct = bi & 3;
        const int hw_l = tid & 63, cg = tid >> 6;
        const float* src = x + ((size_t)(b * 256 + ct * 64 + cg * 16) << 12)
                             + ht * 64 + hw_l;
        #pragma unroll
        for (int i = 0; i < 16; i++)
            tile[hw_l][cg * 16 + i] = (__bf16)src[(size_t)i << 12];
        __syncthreads();
        const int hw_o = tid >> 2, cq = tid & 3;
        __bf16* dst = xT + ((size_t)(b * HW + ht * 64 + hw_o) << 8)
                         + ct * 64 + cq * 16;
        *(bf16x8*)dst       = *(const bf16x8*)&tile[hw_o][cq * 16];
        *(bf16x8*)(dst + 8) = *(const bf16x8*)&tile[hw_o][cq * 16 + 8];
    } else if (bi < 576) {
        const int b2 = bi - 512;
        const int nb = b2 >> 2, qtr = b2 & 3;
        #pragma unroll
        for (int ii = 0; ii < 9; ii++) {
            int m = tid + 256 * ii;
            int base = m * 4;
            int o_l = base / 576;
            int f = base - o_l * 576;
            float4 v = *(const float4*)(w_dcn
                + (size_t)(nb * 16 + o_l) * 2304 + qtr * 576 + f);
            lw[o_l][f]     = (__bf16)v.x;
            lw[o_l][f + 1] = (__bf16)v.y;
            lw[o_l][f + 2] = (__bf16)v.z;
            lw[o_l][f + 3] = (__bf16)v.w;
        }
        __syncthreads();
        for (int p = tid; p < 1152; p += 256) {
            int lane = p & 63, seg = p >> 6;
            int tap = seg >> 1, ks = seg & 1;
            int kb = tap * 4 + qtr;
            int o_l = lane & 15, kq = (lane >> 4) & 3;
            bf16x8 v;
            #pragma unroll
            for (int j = 0; j < 8; j++)
                v[j] = lw[o_l][(ks * 32 + kq * 8 + j) * 9 + tap];
            *(bf16x8*)(wbfS
                + ((size_t)(((kb * 2 + ks) * 16 + nb) * 64 + lane)) * 8) = v;
        }
    } else {
        int t = (bi - 576) * 256 + tid;
        int l = t & 63;
        int nf = (t >> 6) & 1;
        int ks = (t >> 7) & 1;
        int kb = t >> 8;
        int o = nf * 16 + (l & 15);
        int kq = (l >> 4) & 3;
        bf16x8 v;
        #pragma unroll
        for (int j = 0; j < 8; j++) {
            int K = kb * 64 + ks * 32 + kq * 8 + j;
            v[j] = (o < OCH) ? (__bf16)w_off[o * 2304 + (K & 255) * 9 + (K >> 8)]
                             : (__bf16)0.f;
        }
        *(bf16x8*)(woffS + (size_t)t * 8) = v;
    }
}

// ---------------------------------------------------------------------------
// MEGA-FUSED kernel — R2 body with ROLLED k-loops (I$ theory test).
// R0-R3 established the 47us fused time is invariant to occupancy, data
// traffic, and (confounded) pipelining; static pipe work sums to ~half the
// measured cycles. Remaining candidate: the ~23KB straight-line body
// streams through the 32KB I$ once per wave with no reuse -> front-end
// stall invisible to MfmaUtil/VALUBusy. Fix under test: #pragma unroll 1
// on the phase -1 and main k-loops -> ~2.5KB hot loop bodies, reused 9x.
// Everything else is R2 verbatim (single-variable).
// ---------------------------------------------------------------------------
union SU {
    float sD[8][2][16][33];   // phase -1 partials (33.8 KB)
    float sC[4][32][133];     // main K-reduction, half-N passes (68.1 KB)
};

__global__ __launch_bounds__(512, 2) void fused_kernel(
    const __bf16* __restrict__ xT, const __bf16* __restrict__ wbfS,
    const __bf16* __restrict__ woffS, const float* __restrict__ b_off,
    const float* __restrict__ gamma, const float* __restrict__ beta,
    const float* __restrict__ rmean, const float* __restrict__ rvar,
    float* __restrict__ out)
{
    __shared__ SU u;
    __shared__ float  sOm[32][33];       // 4.2 KB
    __shared__ int4   sO[9][32];         // 4.6 KB
    __shared__ float4 sW[9][32];         // 4.6 KB

    const int tid = threadIdx.x, wv = tid >> 6, lane = tid & 63;
    const int g = (blockIdx.x & 7) * 32 + (blockIdx.x >> 3);   // XCD swizzle
    const int pixBase = g * 32;
    const int b = pixBase >> 12;
    const int hwBase = pixBase & 4095;
    const int h = hwBase >> 6, w0 = hwBase & 63;   // 32 pixels in one row
    const int n15 = lane & 15, q4 = lane >> 4;

    const int cc  = wv >> 1;             // channel quarter (0..3)
    const int ksw = wv & 1;              // 32-ch half within quarter
    const char* xb = (const char*)xT + ((size_t)b << 12) * 512;
    const int chOffB = (cc * 64 + ksw * 32 + q4 * 8) * 2;  // byte off in row

    // ---------------- Phase -1: offset conv for 32 pixels (ROLLED) -------
    {
        f32x4 acc2[2][2];                // [nf][tile]
        #pragma unroll
        for (int nf = 0; nf < 2; nf++)
            #pragma unroll
            for (int t = 0; t < 2; t++)
                acc2[nf][t] = (f32x4){0.f, 0.f, 0.f, 0.f};

        #pragma unroll 1
        for (int k = 0; k < 9; k++) {
            const int kb = k * 4 + cc;
            const int kh = k / 3, kw = k - kh * 3;
            const int hh = h + kh - 1;
            const int hc = min(max(hh, 0), HH - 1);
            const bool vy = (hh >= 0) && (hh < HH);
            bf16x8 af[2];
            #pragma unroll
            for (int t = 0; t < 2; t++) {
                const int ww = w0 + t * 16 + n15 + kw - 1;
                const bool valid = vy && (ww >= 0) && (ww < WW);
                const int wc = min(max(ww, 0), WW - 1);
                af[t] = *(const bf16x8*)(xb + (size_t)(hc * WW + wc) * 512
                                            + chOffB);
                if (!valid) {
                    #pragma unroll
                    for (int j = 0; j < 8; j++) af[t][j] = (__bf16)0.f;
                }
            }
            #pragma unroll
            for (int nf = 0; nf < 2; nf++) {
                bf16x8 bfr = *(const bf16x8*)(woffS
                    + ((size_t)(((kb * 2 + ksw) * 2 + nf) * 64 + lane)) * 8);
                #pragma unroll
                for (int t = 0; t < 2; t++)
                    acc2[nf][t] = __builtin_amdgcn_mfma_f32_16x16x32_bf16(
                        af[t], bfr, acc2[nf][t], 0, 0, 0);
            }
        }
        #pragma unroll
        for (int nf = 0; nf < 2; nf++)
            #pragma unroll
            for (int t = 0; t < 2; t++)
                #pragma unroll
                for (int r = 0; r < 4; r++)
                    u.sD[wv][t][q4 * 4 + r][nf * 16 + n15] = acc2[nf][t][r];
    }
    __syncthreads();
    for (int t2 = tid; t2 < OCH * 32; t2 += 512) {
        int oc = t2 >> 5, p = t2 & 31;
        float s = b_off[oc];
        #pragma unroll
        for (int w = 0; w < 8; w++) s += u.sD[w][p >> 4][p & 15][oc];
        sOm[oc][p] = s;
    }
    __syncthreads();

    // ---------------- Phase 0: bilinear metadata for 32 pixels -----------
    if (tid < 288) {
        int k = tid >> 5, p = tid & 31;
        float dy = sOm[2 * k][p];
        float dx = sOm[2 * k + 1][p];
        float mm = sOm[18 + k][p];
        mm = 1.f / (1.f + __expf(-mm));
        float py = (float)(h - 1 + k / 3) + dy;
        float px = (float)(w0 + p - 1 + k % 3) + dx;
        float y0f = floorf(py), x0f = floorf(px);
        float ly = py - y0f, lx = px - x0f;
        int y0 = (int)y0f, x0 = (int)x0f;
        int yc0 = min(max(y0, 0), HH - 1),     yc1 = min(max(y0 + 1, 0), HH - 1);
        int xc0 = min(max(x0, 0), WW - 1),     xc1 = min(max(x0 + 1, 0), WW - 1);
        float vy0 = (y0 >= 0 && y0 < HH) ? 1.f : 0.f;
        float vy1 = (y0 + 1 >= 0 && y0 + 1 < HH) ? 1.f : 0.f;
        float vx0 = (x0 >= 0 && x0 < WW) ? 1.f : 0.f;
        float vx1 = (x0 + 1 >= 0 && x0 + 1 < WW) ? 1.f : 0.f;
        sO[k][p] = (int4){(yc0 * WW + xc0) * 512, (yc0 * WW + xc1) * 512,
                          (yc1 * WW + xc0) * 512, (yc1 * WW + xc1) * 512};
        sW[k][p] = (float4){(1.f - ly) * (1.f - lx) * vy0 * vx0 * mm,
                            (1.f - ly) * lx         * vy0 * vx1 * mm,
                            ly         * (1.f - lx) * vy1 * vx0 * mm,
                            ly         * lx         * vy1 * vx1 * mm};
    }
    __syncthreads();

    // ------- Main: barrier-free (cc,ks)-split GEMM, M=32, ROLLED ---------
    f32x4 acc[2][16];                    // [tile][n-col] = 128 regs
    #pragma unroll
    for (int t = 0; t < 2; t++)
        #pragma unroll
        for (int j = 0; j < 16; j++) acc[t][j] = (f32x4){0.f, 0.f, 0.f, 0.f};

    const char* base = xb + chOffB;
    #pragma unroll 1
    for (int k = 0; k < 9; k++) {
        const int kb = k * 4 + cc;
        const int4   O0 = sO[k][n15],      O1 = sO[k][16 + n15];
        const float4 W0 = sW[k][n15],      W1 = sW[k][16 + n15];

        bf16x8 a00 = *(const bf16x8*)(base + O0.x);
        bf16x8 a01 = *(const bf16x8*)(base + O0.y);
        bf16x8 a10 = *(const bf16x8*)(base + O0.z);
        bf16x8 a11 = *(const bf16x8*)(base + O0.w);
        bf16x8 b00 = *(const bf16x8*)(base + O1.x);
        bf16x8 b01 = *(const bf16x8*)(base + O1.y);
        bf16x8 b10 = *(const bf16x8*)(base + O1.z);
        bf16x8 b11 = *(const bf16x8*)(base + O1.w);

        bf16x8 af0, af1;
        #pragma unroll
        for (int j = 0; j < 8; j++) {
            float v0 = W0.x * (float)a00[j] + W0.y * (float)a01[j]
                     + W0.z * (float)a10[j] + W0.w * (float)a11[j];
            float v1 = W1.x * (float)b00[j] + W1.y * (float)b01[j]
                     + W1.z * (float)b10[j] + W1.w * (float)b11[j];
            af0[j] = (__bf16)v0;
            af1[j] = (__bf16)v1;
        }

        const __bf16* wk = wbfS + ((size_t)((kb * 2 + ksw) * 16) * 64 + lane) * 8;
        #pragma unroll
        for (int hf = 0; hf < 2; hf++) {
            bf16x8 bfr[8];
            #pragma unroll
            for (int nb = 0; nb < 8; nb++)
                bfr[nb] = *(const bf16x8*)(wk + (size_t)(hf * 8 + nb) * 512);
            #pragma unroll
            for (int nb = 0; nb < 8; nb++) {
                acc[0][hf * 8 + nb] = __builtin_amdgcn_mfma_f32_16x16x32_bf16(
                    af0, bfr[nb], acc[0][hf * 8 + nb], 0, 0, 0);
                acc[1][hf * 8 + nb] = __builtin_amdgcn_mfma_f32_16x16x32_bf16(
                    af1, bfr[nb], acc[1][hf * 8 + nb], 0, 0, 0);
            }
        }
    }

    // ------- 2-pass cross-wave K-reduction + fused BN/SiLU epilogue -------
    #pragma unroll
    for (int pass = 0; pass < 2; pass++) {
        if (wv < 4) {
            #pragma unroll
            for (int t = 0; t < 2; t++)
                #pragma unroll
                for (int nb = 0; nb < 8; nb++)
                    #pragma unroll
                    for (int r = 0; r < 4; r++)
                        u.sC[wv][t * 16 + q4 * 4 + r][nb * 16 + n15]
                            = acc[t][pass * 8 + nb][r];
        }
        __syncthreads();
        if (wv >= 4) {
            #pragma unroll
            for (int t = 0; t < 2; t++)
                #pragma unroll
                for (int nb = 0; nb < 8; nb++)
                    #pragma unroll
                    for (int r = 0; r < 4; r++)
                        u.sC[wv - 4][t * 16 + q4 * 4 + r][nb * 16 + n15]
                            += acc[t][pass * 8 + nb][r];
        }
        __syncthreads();

        const int px = tid & 31, og = tid >> 5;   // og in [0,16)
        #pragma unroll
        for (int ii = 0; ii < 8; ii++) {
            int col = og * 8 + ii;               // [0,128)
            int o = pass * 128 + col;
            float s = u.sC[0][px][col] + u.sC[1][px][col]
                    + u.sC[2][px][col] + u.sC[3][px][col];
            float inv = gamma[o] * rsqrtf(rvar[o] + EPSV);
            float sh = beta[o] - rmean[o] * inv;
            float y = s * inv + sh;
            out[(size_t)((b * C2 + o) << 12) + hwBase + px]
                = y * (1.f / (1.f + __expf(-y)));
        }
        __syncthreads();
    }
}

// ---------------------------------------------------------------------------
extern "C" void kernel_launch(void* const* d_in, const int* in_sizes, int n_in,
                              void* d_out, int out_size, void* d_ws, size_t ws_size,
                              hipStream_t stream) {
    const float* x      = (const float*)d_in[0];
    const float* w_off  = (const float*)d_in[1];
    const float* b_off  = (const float*)d_in[2];
    const float* w_dcn  = (const float*)d_in[3];
    const float* gamma  = (const float*)d_in[4];
    const float* beta   = (const float*)d_in[5];
    const float* rmean  = (const float*)d_in[6];
    const float* rvar   = (const float*)d_in[7];
    float* out = (float*)d_out;

    char* ws = (char*)d_ws;
    __bf16* wbfS  = (__bf16*)(ws + WBF_OFF);
    __bf16* woffS = (__bf16*)(ws + WOFF_OFF);
    __bf16* xT    = (__bf16*)(ws + XT_OFF);

    prep_kernel<<<612, 256, 0, stream>>>(x, w_dcn, w_off, xT, wbfS, woffS);
    fused_kernel<<<256, 512, 0, stream>>>(xT, wbfS, woffS, b_off,
                                          gamma, beta, rmean, rvar, out);
}

// Round 6
// 117.331 us; speedup vs baseline: 2.2165x; 1.0213x over previous
//
#include <hip/hip_runtime.h>
#include <hip/hip_bf16.h>
#include <math.h>

typedef __bf16 bf16x8 __attribute__((ext_vector_type(8)));
typedef float  f32x4  __attribute__((ext_vector_type(4)));

#define BB 2
#define C1 256
#define C2 256
#define HH 64
#define WW 64
#define HW 4096
#define OCH 27
#define EPSV 1e-5f

// workspace layout (bytes)
#define WBF_OFF  0u          // frag-ordered w_dcn (1.18 MB)
#define WOFF_OFF 1179648u    // frag-ordered w_off
#define XT_OFF   1327104u    // 2*4096*256 bf16 = 4 MB (HWC)

// ---------------------------------------------------------------------------
// MERGED prep kernel (unchanged).
// ---------------------------------------------------------------------------
__global__ __launch_bounds__(256) void prep_kernel(
    const float* __restrict__ x, const float* __restrict__ w_dcn,
    const float* __restrict__ w_off, __bf16* __restrict__ xT,
    __bf16* __restrict__ wbfS, __bf16* __restrict__ woffS)
{
    __shared__ __bf16 tile[64][72];
    __shared__ __bf16 lw[16][584];
    const int bi = blockIdx.x, tid = threadIdx.x;

    if (bi < 512) {
        const int b = bi >> 8;
        const int ht = (bi & 255) >> 2;
        const int ct = bi & 3;
        const int hw_l = tid & 63, cg = tid >> 6;
        const float* src = x + ((size_t)(b * 256 + ct * 64 + cg * 16) << 12)
                             + ht * 64 + hw_l;
        #pragma unroll
        for (int i = 0; i < 16; i++)
            tile[hw_l][cg * 16 + i] = (__bf16)src[(size_t)i << 12];
        __syncthreads();
        const int hw_o = tid >> 2, cq = tid & 3;
        __bf16* dst = xT + ((size_t)(b * HW + ht * 64 + hw_o) << 8)
                         + ct * 64 + cq * 16;
        *(bf16x8*)dst       = *(const bf16x8*)&tile[hw_o][cq * 16];
        *(bf16x8*)(dst + 8) = *(const bf16x8*)&tile[hw_o][cq * 16 + 8];
    } else if (bi < 576) {
        const int b2 = bi - 512;
        const int nb = b2 >> 2, qtr = b2 & 3;
        #pragma unroll
        for (int ii = 0; ii < 9; ii++) {
            int m = tid + 256 * ii;
            int base = m * 4;
            int o_l = base / 576;
            int f = base - o_l * 576;
            float4 v = *(const float4*)(w_dcn
                + (size_t)(nb * 16 + o_l) * 2304 + qtr * 576 + f);
            lw[o_l][f]     = (__bf16)v.x;
            lw[o_l][f + 1] = (__bf16)v.y;
            lw[o_l][f + 2] = (__bf16)v.z;
            lw[o_l][f + 3] = (__bf16)v.w;
        }
        __syncthreads();
        for (int p = tid; p < 1152; p += 256) {
            int lane = p & 63, seg = p >> 6;
            int tap = seg >> 1, ks = seg & 1;
            int kb = tap * 4 + qtr;
            int o_l = lane & 15, kq = (lane >> 4) & 3;
            bf16x8 v;
            #pragma unroll
            for (int j = 0; j < 8; j++)
                v[j] = lw[o_l][(ks * 32 + kq * 8 + j) * 9 + tap];
            *(bf16x8*)(wbfS
                + ((size_t)(((kb * 2 + ks) * 16 + nb) * 64 + lane)) * 8) = v;
        }
    } else {
        int t = (bi - 576) * 256 + tid;
        int l = t & 63;
        int nf = (t >> 6) & 1;
        int ks = (t >> 7) & 1;
        int kb = t >> 8;
        int o = nf * 16 + (l & 15);
        int kq = (l >> 4) & 3;
        bf16x8 v;
        #pragma unroll
        for (int j = 0; j < 8; j++) {
            int K = kb * 64 + ks * 32 + kq * 8 + j;
            v[j] = (o < OCH) ? (__bf16)w_off[o * 2304 + (K & 255) * 9 + (K >> 8)]
                             : (__bf16)0.f;
        }
        *(bf16x8*)(woffS + (size_t)t * 8) = v;
    }
}

// ---------------------------------------------------------------------------
// MEGA-FUSED kernel — R5 base + 2-stage gather prefetch, UN-POISONED.
// R3's pipeline test spilled because launch_bounds(512,2) capped VGPRs at
// 128 while the prefetch double-buffer needs +64. At 512 threads the block
// places exactly 2 waves/SIMD, and 2x256 VGPRs fit the per-SIMD pool, so
// launch_bounds(512,1) raises the cap to 256: prefetch fits, no spill.
// Spill guard for this round's read: FETCH_SIZE must stay ~7.7MB and
// WRITE_SIZE 8.2MB. Theory under test: per-iter exposed L2 gather latency
// (~400cyc x 9 taps, 2 phase-correlated waves/SIMD) is the dominant cost;
// issuing tap k+1's 8 gathers before tap k's interp+MFMA hides it.
// ---------------------------------------------------------------------------
union SU {
    float sD[8][2][16][33];   // phase -1 partials (33.8 KB)
    float sC[4][32][133];     // main K-reduction, half-N passes (68.1 KB)
};

#define ISSUE_G(p0,p1,p2,p3,p4,p5,p6,p7, kidx)                              \
  {                                                                         \
    const int4 _O0 = sO[kidx][n15];                                         \
    const int4 _O1 = sO[kidx][16 + n15];                                    \
    p0 = *(const bf16x8*)(base + _O0.x);                                    \
    p1 = *(const bf16x8*)(base + _O0.y);                                    \
    p2 = *(const bf16x8*)(base + _O0.z);                                    \
    p3 = *(const bf16x8*)(base + _O0.w);                                    \
    p4 = *(const bf16x8*)(base + _O1.x);                                    \
    p5 = *(const bf16x8*)(base + _O1.y);                                    \
    p6 = *(const bf16x8*)(base + _O1.z);                                    \
    p7 = *(const bf16x8*)(base + _O1.w);                                    \
  }

#define COMPUTE_K(kidx, c00,c01,c10,c11,d00,d01,d10,d11)                    \
  {                                                                         \
    const float4 _W0 = sW[kidx][n15];                                       \
    const float4 _W1 = sW[kidx][16 + n15];                                  \
    const int _kb = (kidx) * 4 + cc;                                        \
    bf16x8 af0, af1;                                                        \
    _Pragma("unroll")                                                       \
    for (int j = 0; j < 8; j++) {                                           \
      float v0 = _W0.x * (float)(c00)[j] + _W0.y * (float)(c01)[j]          \
               + _W0.z * (float)(c10)[j] + _W0.w * (float)(c11)[j];         \
      float v1 = _W1.x * (float)(d00)[j] + _W1.y * (float)(d01)[j]          \
               + _W1.z * (float)(d10)[j] + _W1.w * (float)(d11)[j];         \
      af0[j] = (__bf16)v0; af1[j] = (__bf16)v1;                             \
    }                                                                       \
    const __bf16* _wk = wbfS + ((size_t)((_kb * 2 + ksw) * 16) * 64 + lane) * 8; \
    _Pragma("unroll")                                                       \
    for (int hf = 0; hf < 2; hf++) {                                        \
      bf16x8 bfr[8];                                                        \
      _Pragma("unroll")                                                     \
      for (int nb = 0; nb < 8; nb++)                                        \
        bfr[nb] = *(const bf16x8*)(_wk + (size_t)(hf * 8 + nb) * 512);      \
      _Pragma("unroll")                                                     \
      for (int nb = 0; nb < 8; nb++) {                                      \
        acc[0][hf * 8 + nb] = __builtin_amdgcn_mfma_f32_16x16x32_bf16(      \
            af0, bfr[nb], acc[0][hf * 8 + nb], 0, 0, 0);                    \
        acc[1][hf * 8 + nb] = __builtin_amdgcn_mfma_f32_16x16x32_bf16(      \
            af1, bfr[nb], acc[1][hf * 8 + nb], 0, 0, 0);                    \
      }                                                                     \
    }                                                                       \
  }

__global__ __launch_bounds__(512, 1) void fused_kernel(
    const __bf16* __restrict__ xT, const __bf16* __restrict__ wbfS,
    const __bf16* __restrict__ woffS, const float* __restrict__ b_off,
    const float* __restrict__ gamma, const float* __restrict__ beta,
    const float* __restrict__ rmean, const float* __restrict__ rvar,
    float* __restrict__ out)
{
    __shared__ SU u;
    __shared__ float  sOm[32][33];       // 4.2 KB
    __shared__ int4   sO[9][32];         // 4.6 KB
    __shared__ float4 sW[9][32];         // 4.6 KB

    const int tid = threadIdx.x, wv = tid >> 6, lane = tid & 63;
    const int g = (blockIdx.x & 7) * 32 + (blockIdx.x >> 3);   // XCD swizzle
    const int pixBase = g * 32;
    const int b = pixBase >> 12;
    const int hwBase = pixBase & 4095;
    const int h = hwBase >> 6, w0 = hwBase & 63;   // 32 pixels in one row
    const int n15 = lane & 15, q4 = lane >> 4;

    const int cc  = wv >> 1;             // channel quarter (0..3)
    const int ksw = wv & 1;              // 32-ch half within quarter
    const char* xb = (const char*)xT + ((size_t)b << 12) * 512;
    const int chOffB = (cc * 64 + ksw * 32 + q4 * 8) * 2;  // byte off in row

    // ---------------- Phase -1: offset conv for 32 pixels (ROLLED) -------
    {
        f32x4 acc2[2][2];                // [nf][tile]
        #pragma unroll
        for (int nf = 0; nf < 2; nf++)
            #pragma unroll
            for (int t = 0; t < 2; t++)
                acc2[nf][t] = (f32x4){0.f, 0.f, 0.f, 0.f};

        #pragma unroll 1
        for (int k = 0; k < 9; k++) {
            const int kb = k * 4 + cc;
            const int kh = k / 3, kw = k - kh * 3;
            const int hh = h + kh - 1;
            const int hc = min(max(hh, 0), HH - 1);
            const bool vy = (hh >= 0) && (hh < HH);
            bf16x8 af[2];
            #pragma unroll
            for (int t = 0; t < 2; t++) {
                const int ww = w0 + t * 16 + n15 + kw - 1;
                const bool valid = vy && (ww >= 0) && (ww < WW);
                const int wc = min(max(ww, 0), WW - 1);
                af[t] = *(const bf16x8*)(xb + (size_t)(hc * WW + wc) * 512
                                            + chOffB);
                if (!valid) {
                    #pragma unroll
                    for (int j = 0; j < 8; j++) af[t][j] = (__bf16)0.f;
                }
            }
            #pragma unroll
            for (int nf = 0; nf < 2; nf++) {
                bf16x8 bfr = *(const bf16x8*)(woffS
                    + ((size_t)(((kb * 2 + ksw) * 2 + nf) * 64 + lane)) * 8);
                #pragma unroll
                for (int t = 0; t < 2; t++)
                    acc2[nf][t] = __builtin_amdgcn_mfma_f32_16x16x32_bf16(
                        af[t], bfr, acc2[nf][t], 0, 0, 0);
            }
        }
        #pragma unroll
        for (int nf = 0; nf < 2; nf++)
            #pragma unroll
            for (int t = 0; t < 2; t++)
                #pragma unroll
                for (int r = 0; r < 4; r++)
                    u.sD[wv][t][q4 * 4 + r][nf * 16 + n15] = acc2[nf][t][r];
    }
    __syncthreads();
    for (int t2 = tid; t2 < OCH * 32; t2 += 512) {
        int oc = t2 >> 5, p = t2 & 31;
        float s = b_off[oc];
        #pragma unroll
        for (int w = 0; w < 8; w++) s += u.sD[w][p >> 4][p & 15][oc];
        sOm[oc][p] = s;
    }
    __syncthreads();

    // ---------------- Phase 0: bilinear metadata for 32 pixels -----------
    if (tid < 288) {
        int k = tid >> 5, p = tid & 31;
        float dy = sOm[2 * k][p];
        float dx = sOm[2 * k + 1][p];
        float mm = sOm[18 + k][p];
        mm = 1.f / (1.f + __expf(-mm));
        float py = (float)(h - 1 + k / 3) + dy;
        float px = (float)(w0 + p - 1 + k % 3) + dx;
        float y0f = floorf(py), x0f = floorf(px);
        float ly = py - y0f, lx = px - x0f;
        int y0 = (int)y0f, x0 = (int)x0f;
        int yc0 = min(max(y0, 0), HH - 1),     yc1 = min(max(y0 + 1, 0), HH - 1);
        int xc0 = min(max(x0, 0), WW - 1),     xc1 = min(max(x0 + 1, 0), WW - 1);
        float vy0 = (y0 >= 0 && y0 < HH) ? 1.f : 0.f;
        float vy1 = (y0 + 1 >= 0 && y0 + 1 < HH) ? 1.f : 0.f;
        float vx0 = (x0 >= 0 && x0 < WW) ? 1.f : 0.f;
        float vx1 = (x0 + 1 >= 0 && x0 + 1 < WW) ? 1.f : 0.f;
        sO[k][p] = (int4){(yc0 * WW + xc0) * 512, (yc0 * WW + xc1) * 512,
                          (yc1 * WW + xc0) * 512, (yc1 * WW + xc1) * 512};
        sW[k][p] = (float4){(1.f - ly) * (1.f - lx) * vy0 * vx0 * mm,
                            (1.f - ly) * lx         * vy0 * vx1 * mm,
                            ly         * (1.f - lx) * vy1 * vx0 * mm,
                            ly         * lx         * vy1 * vx1 * mm};
    }
    __syncthreads();

    // ------- Main: pipelined barrier-free (cc,ks)-split GEMM, M=32 -------
    f32x4 acc[2][16];                    // [tile][n-col] = 128 regs
    #pragma unroll
    for (int t = 0; t < 2; t++)
        #pragma unroll
        for (int j = 0; j < 16; j++) acc[t][j] = (f32x4){0.f, 0.f, 0.f, 0.f};

    const char* base = xb + chOffB;

    bf16x8 g0, g1, g2, g3, g4, g5, g6, g7;   // stage A gathers
    bf16x8 h0, h1, h2, h3, h4, h5, h6, h7;   // stage B gathers

    ISSUE_G(g0, g1, g2, g3, g4, g5, g6, g7, 0)

    #pragma unroll 1
    for (int kk = 0; kk < 4; kk++) {
        const int ke = 2 * kk, ko = 2 * kk + 1;
        // prefetch tap ko while computing tap ke
        ISSUE_G(h0, h1, h2, h3, h4, h5, h6, h7, ko)
        COMPUTE_K(ke, g0, g1, g2, g3, g4, g5, g6, g7)
        // prefetch tap ko+1 while computing tap ko
        ISSUE_G(g0, g1, g2, g3, g4, g5, g6, g7, ko + 1)
        COMPUTE_K(ko, h0, h1, h2, h3, h4, h5, h6, h7)
    }
    // tail tap 8 (gathers already in flight)
    COMPUTE_K(8, g0, g1, g2, g3, g4, g5, g6, g7)

    // ------- 2-pass cross-wave K-reduction + fused BN/SiLU epilogue -------
    #pragma unroll
    for (int pass = 0; pass < 2; pass++) {
        if (wv < 4) {
            #pragma unroll
            for (int t = 0; t < 2; t++)
                #pragma unroll
                for (int nb = 0; nb < 8; nb++)
                    #pragma unroll
                    for (int r = 0; r < 4; r++)
                        u.sC[wv][t * 16 + q4 * 4 + r][nb * 16 + n15]
                            = acc[t][pass * 8 + nb][r];
        }
        __syncthreads();
        if (wv >= 4) {
            #pragma unroll
            for (int t = 0; t < 2; t++)
                #pragma unroll
                for (int nb = 0; nb < 8; nb++)
                    #pragma unroll
                    for (int r = 0; r < 4; r++)
                        u.sC[wv - 4][t * 16 + q4 * 4 + r][nb * 16 + n15]
                            += acc[t][pass * 8 + nb][r];
        }
        __syncthreads();

        const int px = tid & 31, og = tid >> 5;   // og in [0,16)
        #pragma unroll
        for (int ii = 0; ii < 8; ii++) {
            int col = og * 8 + ii;               // [0,128)
            int o = pass * 128 + col;
            float s = u.sC[0][px][col] + u.sC[1][px][col]
                    + u.sC[2][px][col] + u.sC[3][px][col];
            float inv = gamma[o] * rsqrtf(rvar[o] + EPSV);
            float sh = beta[o] - rmean[o] * inv;
            float y = s * inv + sh;
            out[(size_t)((b * C2 + o) << 12) + hwBase + px]
                = y * (1.f / (1.f + __expf(-y)));
        }
        __syncthreads();
    }
}

// ---------------------------------------------------------------------------
extern "C" void kernel_launch(void* const* d_in, const int* in_sizes, int n_in,
                              void* d_out, int out_size, void* d_ws, size_t ws_size,
                              hipStream_t stream) {
    const float* x      = (const float*)d_in[0];
    const float* w_off  = (const float*)d_in[1];
    const float* b_off  = (const float*)d_in[2];
    const float* w_dcn  = (const float*)d_in[3];
    const float* gamma  = (const float*)d_in[4];
    const float* beta   = (const float*)d_in[5];
    const float* rmean  = (const float*)d_in[6];
    const float* rvar   = (const float*)d_in[7];
    float* out = (float*)d_out;

    char* ws = (char*)d_ws;
    __bf16* wbfS  = (__bf16*)(ws + WBF_OFF);
    __bf16* woffS = (__bf16*)(ws + WOFF_OFF);
    __bf16* xT    = (__bf16*)(ws + XT_OFF);

    prep_kernel<<<612, 256, 0, stream>>>(x, w_dcn, w_off, xT, wbfS, woffS);
    fused_kernel<<<256, 512, 0, stream>>>(xT, wbfS, woffS, b_off,
                                          gamma, beta, rmean, rvar, out);
}

// Round 7
// 116.403 us; speedup vs baseline: 2.2342x; 1.0080x over previous
//
#include <hip/hip_runtime.h>
#include <hip/hip_bf16.h>
#include <math.h>

typedef __bf16 bf16x8 __attribute__((ext_vector_type(8)));
typedef float  f32x4  __attribute__((ext_vector_type(4)));

#define BB 2
#define C1 256
#define C2 256
#define HH 64
#define WW 64
#define HW 4096
#define OCH 27
#define EPSV 1e-5f

// workspace layout (bytes)
#define WBF_OFF  0u          // frag-ordered w_dcn (1.18 MB)
#define WOFF_OFF 1179648u    // frag-ordered w_off
#define XT_OFF   1327104u    // 2*4096*256 bf16 = 4 MB (HWC)

// ---------------------------------------------------------------------------
// MERGED prep kernel — XCD-ALIGNED transpose indexing (only change vs R6).
// Fused block with bid&7==X reads pixel rows [16X,16X+16) of batch X>>2.
// Dispatch round-robins workgroups over XCDs (XCD = bid%8), so re-indexing
// the transpose part as T=bi&7, j=bi>>3 -> (b=T>>2, h=(T&3)*16+(j>>2),
// ct=j&3) makes each xT row-block get WRITTEN on the XCD whose L2 the
// consuming fused block will READ from. xT slice/XCD = 512KB << 4MB L2.
// Expected signature: FETCH_SIZE drops by ~4MB (xT no longer HBM-fetched).
// ---------------------------------------------------------------------------
__global__ __launch_bounds__(256) void prep_kernel(
    const float* __restrict__ x, const float* __restrict__ w_dcn,
    const float* __restrict__ w_off, __bf16* __restrict__ xT,
    __bf16* __restrict__ wbfS, __bf16* __restrict__ woffS)
{
    __shared__ __bf16 tile[64][72];
    __shared__ __bf16 lw[16][584];
    const int bi = blockIdx.x, tid = threadIdx.x;

    if (bi < 512) {
        const int T = bi & 7, j = bi >> 3;
        const int b = T >> 2;
        const int ht = (T & 3) * 16 + (j >> 2);
        const int ct = j & 3;
        const int hw_l = tid & 63, cg = tid >> 6;
        const float* src = x + ((size_t)(b * 256 + ct * 64 + cg * 16) << 12)
                             + ht * 64 + hw_l;
        #pragma unroll
        for (int i = 0; i < 16; i++)
            tile[hw_l][cg * 16 + i] = (__bf16)src[(size_t)i << 12];
        __syncthreads();
        const int hw_o = tid >> 2, cq = tid & 3;
        __bf16* dst = xT + ((size_t)(b * HW + ht * 64 + hw_o) << 8)
                         + ct * 64 + cq * 16;
        *(bf16x8*)dst       = *(const bf16x8*)&tile[hw_o][cq * 16];
        *(bf16x8*)(dst + 8) = *(const bf16x8*)&tile[hw_o][cq * 16 + 8];
    } else if (bi < 576) {
        const int b2 = bi - 512;
        const int nb = b2 >> 2, qtr = b2 & 3;
        #pragma unroll
        for (int ii = 0; ii < 9; ii++) {
            int m = tid + 256 * ii;
            int base = m * 4;
            int o_l = base / 576;
            int f = base - o_l * 576;
            float4 v = *(const float4*)(w_dcn
                + (size_t)(nb * 16 + o_l) * 2304 + qtr * 576 + f);
            lw[o_l][f]     = (__bf16)v.x;
            lw[o_l][f + 1] = (__bf16)v.y;
            lw[o_l][f + 2] = (__bf16)v.z;
            lw[o_l][f + 3] = (__bf16)v.w;
        }
        __syncthreads();
        for (int p = tid; p < 1152; p += 256) {
            int lane = p & 63, seg = p >> 6;
            int tap = seg >> 1, ks = seg & 1;
            int kb = tap * 4 + qtr;
            int o_l = lane & 15, kq = (lane >> 4) & 3;
            bf16x8 v;
            #pragma unroll
            for (int j = 0; j < 8; j++)
                v[j] = lw[o_l][(ks * 32 + kq * 8 + j) * 9 + tap];
            *(bf16x8*)(wbfS
                + ((size_t)(((kb * 2 + ks) * 16 + nb) * 64 + lane)) * 8) = v;
        }
    } else {
        int t = (bi - 576) * 256 + tid;
        int l = t & 63;
        int nf = (t >> 6) & 1;
        int ks = (t >> 7) & 1;
        int kb = t >> 8;
        int o = nf * 16 + (l & 15);
        int kq = (l >> 4) & 3;
        bf16x8 v;
        #pragma unroll
        for (int j = 0; j < 8; j++) {
            int K = kb * 64 + ks * 32 + kq * 8 + j;
            v[j] = (o < OCH) ? (__bf16)w_off[o * 2304 + (K & 255) * 9 + (K >> 8)]
                             : (__bf16)0.f;
        }
        *(bf16x8*)(woffS + (size_t)t * 8) = v;
    }
}

// ---------------------------------------------------------------------------
// MEGA-FUSED kernel — byte-identical to R6 (pipelined M=32, rolled loops).
// ---------------------------------------------------------------------------
union SU {
    float sD[8][2][16][33];   // phase -1 partials (33.8 KB)
    float sC[4][32][133];     // main K-reduction, half-N passes (68.1 KB)
};

#define ISSUE_G(p0,p1,p2,p3,p4,p5,p6,p7, kidx)                              \
  {                                                                         \
    const int4 _O0 = sO[kidx][n15];                                         \
    const int4 _O1 = sO[kidx][16 + n15];                                    \
    p0 = *(const bf16x8*)(base + _O0.x);                                    \
    p1 = *(const bf16x8*)(base + _O0.y);                                    \
    p2 = *(const bf16x8*)(base + _O0.z);                                    \
    p3 = *(const bf16x8*)(base + _O0.w);                                    \
    p4 = *(const bf16x8*)(base + _O1.x);                                    \
    p5 = *(const bf16x8*)(base + _O1.y);                                    \
    p6 = *(const bf16x8*)(base + _O1.z);                                    \
    p7 = *(const bf16x8*)(base + _O1.w);                                    \
  }

#define COMPUTE_K(kidx, c00,c01,c10,c11,d00,d01,d10,d11)                    \
  {                                                                         \
    const float4 _W0 = sW[kidx][n15];                                       \
    const float4 _W1 = sW[kidx][16 + n15];                                  \
    const int _kb = (kidx) * 4 + cc;                                        \
    bf16x8 af0, af1;                                                        \
    _Pragma("unroll")                                                       \
    for (int j = 0; j < 8; j++) {                                           \
      float v0 = _W0.x * (float)(c00)[j] + _W0.y * (float)(c01)[j]          \
               + _W0.z * (float)(c10)[j] + _W0.w * (float)(c11)[j];         \
      float v1 = _W1.x * (float)(d00)[j] + _W1.y * (float)(d01)[j]          \
               + _W1.z * (float)(d10)[j] + _W1.w * (float)(d11)[j];         \
      af0[j] = (__bf16)v0; af1[j] = (__bf16)v1;                             \
    }                                                                       \
    const __bf16* _wk = wbfS + ((size_t)((_kb * 2 + ksw) * 16) * 64 + lane) * 8; \
    _Pragma("unroll")                                                       \
    for (int hf = 0; hf < 2; hf++) {                                        \
      bf16x8 bfr[8];                                                        \
      _Pragma("unroll")                                                     \
      for (int nb = 0; nb < 8; nb++)                                        \
        bfr[nb] = *(const bf16x8*)(_wk + (size_t)(hf * 8 + nb) * 512);      \
      _Pragma("unroll")                                                     \
      for (int nb = 0; nb < 8; nb++) {                                      \
        acc[0][hf * 8 + nb] = __builtin_amdgcn_mfma_f32_16x16x32_bf16(      \
            af0, bfr[nb], acc[0][hf * 8 + nb], 0, 0, 0);                    \
        acc[1][hf * 8 + nb] = __builtin_amdgcn_mfma_f32_16x16x32_bf16(      \
            af1, bfr[nb], acc[1][hf * 8 + nb], 0, 0, 0);                    \
      }                                                                     \
    }                                                                       \
  }

__global__ __launch_bounds__(512, 1) void fused_kernel(
    const __bf16* __restrict__ xT, const __bf16* __restrict__ wbfS,
    const __bf16* __restrict__ woffS, const float* __restrict__ b_off,
    const float* __restrict__ gamma, const float* __restrict__ beta,
    const float* __restrict__ rmean, const float* __restrict__ rvar,
    float* __restrict__ out)
{
    __shared__ SU u;
    __shared__ float  sOm[32][33];       // 4.2 KB
    __shared__ int4   sO[9][32];         // 4.6 KB
    __shared__ float4 sW[9][32];         // 4.6 KB

    const int tid = threadIdx.x, wv = tid >> 6, lane = tid & 63;
    const int g = (blockIdx.x & 7) * 32 + (blockIdx.x >> 3);   // XCD swizzle
    const int pixBase = g * 32;
    const int b = pixBase >> 12;
    const int hwBase = pixBase & 4095;
    const int h = hwBase >> 6, w0 = hwBase & 63;   // 32 pixels in one row
    const int n15 = lane & 15, q4 = lane >> 4;

    const int cc  = wv >> 1;             // channel quarter (0..3)
    const int ksw = wv & 1;              // 32-ch half within quarter
    const char* xb = (const char*)xT + ((size_t)b << 12) * 512;
    const int chOffB = (cc * 64 + ksw * 32 + q4 * 8) * 2;  // byte off in row

    // ---------------- Phase -1: offset conv for 32 pixels (ROLLED) -------
    {
        f32x4 acc2[2][2];                // [nf][tile]
        #pragma unroll
        for (int nf = 0; nf < 2; nf++)
            #pragma unroll
            for (int t = 0; t < 2; t++)
                acc2[nf][t] = (f32x4){0.f, 0.f, 0.f, 0.f};

        #pragma unroll 1
        for (int k = 0; k < 9; k++) {
            const int kb = k * 4 + cc;
            const int kh = k / 3, kw = k - kh * 3;
            const int hh = h + kh - 1;
            const int hc = min(max(hh, 0), HH - 1);
            const bool vy = (hh >= 0) && (hh < HH);
            bf16x8 af[2];
            #pragma unroll
            for (int t = 0; t < 2; t++) {
                const int ww = w0 + t * 16 + n15 + kw - 1;
                const bool valid = vy && (ww >= 0) && (ww < WW);
                const int wc = min(max(ww, 0), WW - 1);
                af[t] = *(const bf16x8*)(xb + (size_t)(hc * WW + wc) * 512
                                            + chOffB);
                if (!valid) {
                    #pragma unroll
                    for (int j = 0; j < 8; j++) af[t][j] = (__bf16)0.f;
                }
            }
            #pragma unroll
            for (int nf = 0; nf < 2; nf++) {
                bf16x8 bfr = *(const bf16x8*)(woffS
                    + ((size_t)(((kb * 2 + ksw) * 2 + nf) * 64 + lane)) * 8);
                #pragma unroll
                for (int t = 0; t < 2; t++)
                    acc2[nf][t] = __builtin_amdgcn_mfma_f32_16x16x32_bf16(
                        af[t], bfr, acc2[nf][t], 0, 0, 0);
            }
        }
        #pragma unroll
        for (int nf = 0; nf < 2; nf++)
            #pragma unroll
            for (int t = 0; t < 2; t++)
                #pragma unroll
                for (int r = 0; r < 4; r++)
                    u.sD[wv][t][q4 * 4 + r][nf * 16 + n15] = acc2[nf][t][r];
    }
    __syncthreads();
    for (int t2 = tid; t2 < OCH * 32; t2 += 512) {
        int oc = t2 >> 5, p = t2 & 31;
        float s = b_off[oc];
        #pragma unroll
        for (int w = 0; w < 8; w++) s += u.sD[w][p >> 4][p & 15][oc];
        sOm[oc][p] = s;
    }
    __syncthreads();

    // ---------------- Phase 0: bilinear metadata for 32 pixels -----------
    if (tid < 288) {
        int k = tid >> 5, p = tid & 31;
        float dy = sOm[2 * k][p];
        float dx = sOm[2 * k + 1][p];
        float mm = sOm[18 + k][p];
        mm = 1.f / (1.f + __expf(-mm));
        float py = (float)(h - 1 + k / 3) + dy;
        float px = (float)(w0 + p - 1 + k % 3) + dx;
        float y0f = floorf(py), x0f = floorf(px);
        float ly = py - y0f, lx = px - x0f;
        int y0 = (int)y0f, x0 = (int)x0f;
        int yc0 = min(max(y0, 0), HH - 1),     yc1 = min(max(y0 + 1, 0), HH - 1);
        int xc0 = min(max(x0, 0), WW - 1),     xc1 = min(max(x0 + 1, 0), WW - 1);
        float vy0 = (y0 >= 0 && y0 < HH) ? 1.f : 0.f;
        float vy1 = (y0 + 1 >= 0 && y0 + 1 < HH) ? 1.f : 0.f;
        float vx0 = (x0 >= 0 && x0 < WW) ? 1.f : 0.f;
        float vx1 = (x0 + 1 >= 0 && x0 + 1 < WW) ? 1.f : 0.f;
        sO[k][p] = (int4){(yc0 * WW + xc0) * 512, (yc0 * WW + xc1) * 512,
                          (yc1 * WW + xc0) * 512, (yc1 * WW + xc1) * 512};
        sW[k][p] = (float4){(1.f - ly) * (1.f - lx) * vy0 * vx0 * mm,
                            (1.f - ly) * lx         * vy0 * vx1 * mm,
                            ly         * (1.f - lx) * vy1 * vx0 * mm,
                            ly         * lx         * vy1 * vx1 * mm};
    }
    __syncthreads();

    // ------- Main: pipelined barrier-free (cc,ks)-split GEMM, M=32 -------
    f32x4 acc[2][16];                    // [tile][n-col] = 128 regs
    #pragma unroll
    for (int t = 0; t < 2; t++)
        #pragma unroll
        for (int j = 0; j < 16; j++) acc[t][j] = (f32x4){0.f, 0.f, 0.f, 0.f};

    const char* base = xb + chOffB;

    bf16x8 g0, g1, g2, g3, g4, g5, g6, g7;   // stage A gathers
    bf16x8 h0, h1, h2, h3, h4, h5, h6, h7;   // stage B gathers

    ISSUE_G(g0, g1, g2, g3, g4, g5, g6, g7, 0)

    #pragma unroll 1
    for (int kk = 0; kk < 4; kk++) {
        const int ke = 2 * kk, ko = 2 * kk + 1;
        // prefetch tap ko while computing tap ke
        ISSUE_G(h0, h1, h2, h3, h4, h5, h6, h7, ko)
        COMPUTE_K(ke, g0, g1, g2, g3, g4, g5, g6, g7)
        // prefetch tap ko+1 while computing tap ko
        ISSUE_G(g0, g1, g2, g3, g4, g5, g6, g7, ko + 1)
        COMPUTE_K(ko, h0, h1, h2, h3, h4, h5, h6, h7)
    }
    // tail tap 8 (gathers already in flight)
    COMPUTE_K(8, g0, g1, g2, g3, g4, g5, g6, g7)

    // ------- 2-pass cross-wave K-reduction + fused BN/SiLU epilogue -------
    #pragma unroll
    for (int pass = 0; pass < 2; pass++) {
        if (wv < 4) {
            #pragma unroll
            for (int t = 0; t < 2; t++)
                #pragma unroll
                for (int nb = 0; nb < 8; nb++)
                    #pragma unroll
                    for (int r = 0; r < 4; r++)
                        u.sC[wv][t * 16 + q4 * 4 + r][nb * 16 + n15]
                            = acc[t][pass * 8 + nb][r];
        }
        __syncthreads();
        if (wv >= 4) {
            #pragma unroll
            for (int t = 0; t < 2; t++)
                #pragma unroll
                for (int nb = 0; nb < 8; nb++)
                    #pragma unroll
                    for (int r = 0; r < 4; r++)
                        u.sC[wv - 4][t * 16 + q4 * 4 + r][nb * 16 + n15]
                            += acc[t][pass * 8 + nb][r];
        }
        __syncthreads();

        const int px = tid & 31, og = tid >> 5;   // og in [0,16)
        #pragma unroll
        for (int ii = 0; ii < 8; ii++) {
            int col = og * 8 + ii;               // [0,128)
            int o = pass * 128 + col;
            float s = u.sC[0][px][col] + u.sC[1][px][col]
                    + u.sC[2][px][col] + u.sC[3][px][col];
            float inv = gamma[o] * rsqrtf(rvar[o] + EPSV);
            float sh = beta[o] - rmean[o] * inv;
            float y = s * inv + sh;
            out[(size_t)((b * C2 + o) << 12) + hwBase + px]
                = y * (1.f / (1.f + __expf(-y)));
        }
        __syncthreads();
    }
}

// ---------------------------------------------------------------------------
extern "C" void kernel_launch(void* const* d_in, const int* in_sizes, int n_in,
                              void* d_out, int out_size, void* d_ws, size_t ws_size,
                              hipStream_t stream) {
    const float* x      = (const float*)d_in[0];
    const float* w_off  = (const float*)d_in[1];
    const float* b_off  = (const float*)d_in[2];
    const float* w_dcn  = (const float*)d_in[3];
    const float* gamma  = (const float*)d_in[4];
    const float* beta   = (const float*)d_in[5];
    const float* rmean  = (const float*)d_in[6];
    const float* rvar   = (const float*)d_in[7];
    float* out = (float*)d_out;

    char* ws = (char*)d_ws;
    __bf16* wbfS  = (__bf16*)(ws + WBF_OFF);
    __bf16* woffS = (__bf16*)(ws + WOFF_OFF);
    __bf16* xT    = (__bf16*)(ws + XT_OFF);

    prep_kernel<<<612, 256, 0, stream>>>(x, w_dcn, w_off, xT, wbfS, woffS);
    fused_kernel<<<256, 512, 0, stream>>>(xT, wbfS, woffS, b_off,
                                          gamma, beta, rmean, rvar, out);
}